// Round 1
// 179.634 us; speedup vs baseline: 1.1181x; 1.1181x over previous
//
#include <hip/hip_runtime.h>
#include <stdint.h>

typedef short s16x8 __attribute__((ext_vector_type(8)));
typedef float f32x4 __attribute__((ext_vector_type(4)));

#define IN_F   256
#define OUT_F  256
#define BATCH  16384
#define NB     31
#define KONE   8192
#define KTOT   8448

typedef const __attribute__((address_space(1))) void* as1cvp;
typedef __attribute__((address_space(3))) void* as3vp;

__device__ __forceinline__ unsigned short f2bf(float f) {
    unsigned u = __float_as_uint(f);
    u += 0x7FFFu + ((u >> 16) & 1u);   // RNE
    return (unsigned short)(u >> 16);
}
// monotone f32<->uint key for atomic min/max
__device__ __forceinline__ unsigned fkey(float f) {
    unsigned b = __float_as_uint(f);
    return (b & 0x80000000u) ? ~b : (b | 0x80000000u);
}
__device__ __forceinline__ float funkey(unsigned k) {
    return __uint_as_float((k & 0x80000000u) ? (k & 0x7FFFFFFFu) : ~k);
}

// ---------------- kernel 1: column min/max via punned atomics ----------------
// 512 blocks x 32 rows: 2 blocks/CU (was 128 blocks = half the GPU idle).
__global__ void minmax_atomic(const float* __restrict__ x,
                              unsigned* __restrict__ pminP, unsigned* __restrict__ pmaxP) {
    const int t = threadIdx.x;
    const int b0 = blockIdx.x * 32;
    float mn = 3.4e38f, mx = -3.4e38f;
    for (int r = 0; r < 32; ++r) {
        float v = x[(size_t)(b0 + r) * IN_F + t];
        mn = fminf(mn, v);
        mx = fmaxf(mx, v);
    }
    atomicMin(&pminP[t], fkey(mn));
    atomicMax(&pmaxP[t], fkey(mx));
}

// ---------------- kernel 2: build W = [Haar-synthesized V | bw] in bf16 ----------------
// 4-way K-split across blockIdx.y: 1024 blocks (4/CU) instead of 256.
__global__ void build_wb(const float* __restrict__ bw, const float* __restrict__ sw,
                         const float* __restrict__ sc, unsigned short* __restrict__ Wb) {
    const int o = blockIdx.x;
    const int k0 = blockIdx.y * 2112;          // 4 * 2112 = 8448 = KTOT
    const int t = threadIdx.x;
    for (int k = k0 + t; k < k0 + 2112; k += 256) {
        float val;
        if (k < KONE) {
            int i = k >> 5, j = k & 31;
            float s = sc[o * IN_F + i];
            float acc = 0.f;
#pragma unroll
            for (int l = 0; l < 5; ++l) {
                int kk = (1 << l) - 1 + (j >> (5 - l));
                float w = sw[((size_t)(o * IN_F + i)) * NB + kk];
                acc += (((j >> (4 - l)) & 1) ? -w : w);
            }
            val = acc * s;
        } else {
            val = bw[o * IN_F + (k - KONE)];
        }
        Wb[(size_t)o * KTOT + k] = f2bf(val);
    }
}

// ---------------- kernel 3: leaf indices, transposed leaf_t[i][b] ----------------
// Verified chain: xn = (x - xmin) * (1/((xmax-xmin)+1e-8f)), leaf = (int)(xn*32.0f),
// xn>=1.0 -> 255. Changes vs prior: LDS row stride 68B (odd dword stride -> kills the
// 32-way bank conflict of the old 128B stride where every lane hit bank r>>2), and
// 256 blocks x 64 rows (2x parallelism).
__global__ __launch_bounds__(256) void leafk_t(
    const float* __restrict__ x, const unsigned* __restrict__ pminP,
    const unsigned* __restrict__ pmaxP, unsigned char* __restrict__ lt) {
    __shared__ unsigned char lsh[256 * 68];    // [i][r], stride 68, ~17KB
    __shared__ float xminsh[IN_F], rdensh[IN_F];
    const int t = threadIdx.x;
    const int b0 = blockIdx.x * 64;
    {
        float mn = funkey(pminP[t]), mx = funkey(pmaxP[t]);
        xminsh[t] = mn;
        rdensh[t] = 1.0f / (mx - mn + 1e-8f);
    }
    __syncthreads();
    const float xmn = xminsh[t], rdn = rdensh[t];
    for (int r = 0; r < 64; ++r) {
        float v = x[(size_t)(b0 + r) * IN_F + t];
        float xn = (v - xmn) * rdn;
        int l = (int)(xn * 32.0f);
        lsh[t * 68 + r] = (l >= 0 && l < 32) ? (unsigned char)l : (unsigned char)255;
    }
    __syncthreads();
    // coalesced transposed write: 16 lanes write one 64B row of lt per step
    const int lane = t & 63, w = t >> 6;
    const unsigned* lshU = (const unsigned*)lsh;   // row i = lshU[i*17 .. i*17+15]
#pragma unroll
    for (int ib = 0; ib < 16; ++ib) {
        int i = ib * 16 + w * 4 + (lane >> 4);
        unsigned val = lshU[i * 17 + (lane & 15)];
        *(unsigned*)(lt + (size_t)i * BATCH + b0 + (lane & 15) * 4) = val;
    }
}

// ---------------- kernel 4: fused one-hot GEMM, 64x64 tile, TWO-wave blocks ----
// grid (256, 4) = 1024 blocks x 128 threads -> 4 blocks/CU = 8 waves/CU = 2 waves/SIMD
// (was 1 wave/SIMD, MfmaUtil 27.5%). Wave w owns output rows 32w..32w+31 (M-split);
// A tile + double-buffered B are shared; each wave issues half the B glds into its own
// linear LDS range. K-accumulation order per output element is unchanged -> numerics
// identical to the verified single-wave version.
__global__ __launch_bounds__(128, 2) void gemm_kan(
    const float* __restrict__ x,
    const unsigned short* __restrict__ Wb,
    const unsigned char* __restrict__ lt,
    float* __restrict__ out)
{
    __shared__ unsigned short Ash[64 * 64];        // 8KB, XOR-swizzled chunks (shared)
    __shared__ unsigned short Bsh[2 * 64 * 64];    // 16KB double buffer (shared)

    const int t     = threadIdx.x;     // 0..127
    const int lane  = t & 63;
    const int wv    = t >> 6;          // 0,1
    const int mtile = blockIdx.x;
    const int ntile = blockIdx.y;

    // zero A tile once; one-hot writes keep it clean
    {
        uint4 z; z.x = z.y = z.z = z.w = 0u;
        uint4* a4 = (uint4*)Ash;
#pragma unroll
        for (int r = 0; r < 4; ++r) a4[t + r * 128] = z;
    }

    // B glds source base. Wave wv covers rows n = 32*wv + 8q + (lane>>3), q=0..3.
    // Source column pre-swizzled by n&7 (== lane>>3, q- and wv-independent);
    // LDS dest stays linear per wave: Bsh + wv*2048 + q*512 + lane*8 shorts.
    const unsigned char* bbase = (const unsigned char*)(Wb
        + (size_t)(ntile * 64 + wv * 32 + (lane >> 3)) * KTOT
        + (((lane & 7) ^ (lane >> 3)) << 3));

    // one-hot identities: 128 threads -> one (row, feature) task each
    const int am = t >> 1;             // row 0..63
    const int ag = t & 1;              // feature within K-step
    const size_t lrow0 = (size_t)mtile * 64;
    int ps = -1;

    unsigned char lf = lt[(size_t)ag * BATCH + lrow0 + am];

    // issue B(0) into buf0
#pragma unroll
    for (int q = 0; q < 4; ++q)
        __builtin_amdgcn_global_load_lds(
            (as1cvp)(bbase + (size_t)q * 8 * KTOT * 2),
            (as3vp)(uint32_t)(uintptr_t)(Bsh + wv * 2048 + q * 512), 16, 0, 0);
    __syncthreads();   // drains B(0) + Ash zeros

    f32x4 acc[2][4] = {};
    const int rr = lane & 15, kq = lane >> 4;

    for (int kb = 0; kb < 132; ++kb) {
        const int cur = kb & 1;
        // ---- A phase ----
        if (kb < 128) {
            if (ps >= 0) Ash[ps] = 0;
            int l = lf;
            if (l < 32) {
                int c = (ag << 2) + (l >> 3);
                ps = (am << 6) + ((c ^ (am & 7)) << 3) + (l & 7);
                Ash[ps] = 0x3F80;
            } else ps = -1;
        } else {
            // dense relu(x) tail: wave wv overwrites rows 32wv..32wv+31
            const float* xr = x + (size_t)(mtile * 64 + wv * 32) * IN_F + (kb - 128) * 64 + lane;
            const int cslot = (lane >> 3);
#pragma unroll
            for (int m0 = 0; m0 < 32; ++m0) {
                int m = wv * 32 + m0;
                float v = xr[(size_t)m0 * IN_F];
                Ash[(m << 6) + ((cslot ^ (m & 7)) << 3) + (lane & 7)] = f2bf(fmaxf(v, 0.0f));
            }
        }
        __syncthreads();   // B1: A(kb) visible to both waves

        // ---- issue B(kb+1) into alt buffer (overlaps MFMA below) ----
        if (kb + 1 < 132) {
            const unsigned char* src = bbase + (size_t)(kb + 1) * 128;
            unsigned short* dst = Bsh + (1 - cur) * 4096 + wv * 2048;
#pragma unroll
            for (int q = 0; q < 4; ++q)
                __builtin_amdgcn_global_load_lds(
                    (as1cvp)(src + (size_t)q * 8 * KTOT * 2),
                    (as3vp)(uint32_t)(uintptr_t)(dst + q * 512), 16, 0, 0);
        }
        // prefetch leaf byte for kb+1 (lands during MFMA)
        if (kb + 1 < 128) {
            lf = lt[(size_t)((kb + 1) * 2 + ag) * BATCH + lrow0 + am];
        }

        // ---- MFMA phase on buf[cur]: wave wv does rows 32wv..32wv+31 ----
        const unsigned short* bb = Bsh + cur * 4096;
#pragma unroll
        for (int ks = 0; ks < 2; ++ks) {
            const int c = (ks << 2) + kq;
            s16x8 af[2], bfr[4];
#pragma unroll
            for (int mt = 0; mt < 2; ++mt) {
                int m = wv * 32 + mt * 16 + rr;
                af[mt] = *(const s16x8*)&Ash[(m << 6) + ((c ^ (m & 7)) << 3)];
            }
#pragma unroll
            for (int nt = 0; nt < 4; ++nt) {
                int n = nt * 16 + rr;
                bfr[nt] = *(const s16x8*)&bb[(n << 6) + ((c ^ (n & 7)) << 3)];
            }
#pragma unroll
            for (int mt = 0; mt < 2; ++mt)
#pragma unroll
                for (int nt = 0; nt < 4; ++nt)
                    acc[mt][nt] = __builtin_amdgcn_mfma_f32_16x16x32_bf16(
                        af[mt], bfr[nt], acc[mt][nt], 0, 0, 0);
        }
        __syncthreads();   // B2: drains B(kb+1) glds (landed during MFMA)
    }

    // ---- epilogue: C/D layout col=lane&15, row=(lane>>4)*4+reg (m89/m91) ----
    const int rq = lane >> 4;
#pragma unroll
    for (int mt = 0; mt < 2; ++mt)
#pragma unroll
        for (int nt = 0; nt < 4; ++nt)
#pragma unroll
            for (int v = 0; v < 4; ++v) {
                int row = mtile * 64 + wv * 32 + mt * 16 + rq * 4 + v;
                int col = ntile * 64 + nt * 16 + rr;
                out[(size_t)row * OUT_F + col] = acc[mt][nt][v];
            }
}

// ---------------- host ----------------
extern "C" void kernel_launch(void* const* d_in, const int* in_sizes, int n_in,
                              void* d_out, int out_size, void* d_ws, size_t ws_size,
                              hipStream_t stream) {
    (void)in_sizes; (void)n_in; (void)out_size; (void)ws_size;
    const float* x  = (const float*)d_in[0];   // [16384,256]
    const float* bw = (const float*)d_in[1];   // [256,256]
    const float* sw = (const float*)d_in[2];   // [256,256,31]
    const float* sc = (const float*)d_in[3];   // [256,256]
    float* out = (float*)d_out;

    char* ws = (char*)d_ws;
    unsigned short* Wb   = (unsigned short*)ws;                 // 4,325,376
    unsigned char*  lt   = (unsigned char*)(ws + 4325376);      // 4,194,304
    unsigned*       pminP = (unsigned*)(ws + 8519680);          // 1,024
    unsigned*       pmaxP = (unsigned*)(ws + 8520704);          // 1,024

    hipMemsetAsync(pminP, 0xFF, 1024, stream);   // key-max (identity for atomicMin)
    hipMemsetAsync(pmaxP, 0x00, 1024, stream);   // key-min (identity for atomicMax)

    minmax_atomic<<<512, 256, 0, stream>>>(x, pminP, pmaxP);
    build_wb<<<dim3(256, 4), 256, 0, stream>>>(bw, sw, sc, Wb);
    leafk_t<<<256, 256, 0, stream>>>(x, pminP, pmaxP, lt);
    gemm_kan<<<dim3(256, 4), 128, 0, stream>>>(x, Wb, lt, out);
}

// Round 2
// 178.447 us; speedup vs baseline: 1.1255x; 1.0066x over previous
//
#include <hip/hip_runtime.h>
#include <stdint.h>

typedef short s16x8 __attribute__((ext_vector_type(8)));
typedef float f32x4 __attribute__((ext_vector_type(4)));

#define IN_F   256
#define OUT_F  256
#define BATCH  16384
#define NB     31
#define KONE   8192
#define KTOT   8448

typedef const __attribute__((address_space(1))) void* as1cvp;
typedef __attribute__((address_space(3))) void* as3vp;

__device__ __forceinline__ unsigned short f2bf(float f) {
    unsigned u = __float_as_uint(f);
    u += 0x7FFFu + ((u >> 16) & 1u);   // RNE
    return (unsigned short)(u >> 16);
}

// ---------------- kernel 1a: per-block column min/max partials ----------------
// No atomics (R1's 512-deep same-address atomic chains were ~10-15us of serial L2 RMW).
__global__ void minmax_part(const float* __restrict__ x,
                            float* __restrict__ pmn, float* __restrict__ pmx) {
    const int t = threadIdx.x;
    const int b0 = blockIdx.x * 32;
    float mn = 3.4e38f, mx = -3.4e38f;
    for (int r = 0; r < 32; ++r) {
        float v = x[(size_t)(b0 + r) * IN_F + t];
        mn = fminf(mn, v);
        mx = fmaxf(mx, v);
    }
    pmn[blockIdx.x * 256 + t] = mn;    // [block][col], coalesced
    pmx[blockIdx.x * 256 + t] = mx;
}

// ---------------- kernel 1b: reduce 512 partials per column, emit xmin & rden ----
__global__ __launch_bounds__(64) void minmax_reduce(
    const float* __restrict__ pmn, const float* __restrict__ pmx,
    float* __restrict__ xminF, float* __restrict__ rdenF) {
    const int j = blockIdx.x;          // column
    const int lane = threadIdx.x;      // 0..63
    float mn = 3.4e38f, mx = -3.4e38f;
#pragma unroll
    for (int i = 0; i < 8; ++i) {
        int b = lane * 8 + i;          // 0..511
        mn = fminf(mn, pmn[(size_t)b * 256 + j]);
        mx = fmaxf(mx, pmx[(size_t)b * 256 + j]);
    }
#pragma unroll
    for (int off = 32; off; off >>= 1) {
        mn = fminf(mn, __shfl_down(mn, off));
        mx = fmaxf(mx, __shfl_down(mx, off));
    }
    if (lane == 0) {
        xminF[j] = mn;
        rdenF[j] = 1.0f / (mx - mn + 1e-8f);   // verified chain: rcp-mult
    }
}

// ---------------- kernel 2: build W = [Haar-synthesized V | bw] in bf16 ----------------
__global__ void build_wb(const float* __restrict__ bw, const float* __restrict__ sw,
                         const float* __restrict__ sc, unsigned short* __restrict__ Wb) {
    const int o = blockIdx.x;
    const int k0 = blockIdx.y * 2112;          // 4 * 2112 = 8448 = KTOT
    const int t = threadIdx.x;
    for (int k = k0 + t; k < k0 + 2112; k += 256) {
        float val;
        if (k < KONE) {
            int i = k >> 5, j = k & 31;
            float s = sc[o * IN_F + i];
            float acc = 0.f;
#pragma unroll
            for (int l = 0; l < 5; ++l) {
                int kk = (1 << l) - 1 + (j >> (5 - l));
                float w = sw[((size_t)(o * IN_F + i)) * NB + kk];
                acc += (((j >> (4 - l)) & 1) ? -w : w);
            }
            val = acc * s;
        } else {
            val = bw[o * IN_F + (k - KONE)];
        }
        Wb[(size_t)o * KTOT + k] = f2bf(val);
    }
}

// ---------------- kernel 3: leaf indices, transposed leaf_t[i][b] ----------------
// xn = (x - xmin) * rden, leaf = (int)(xn*32.0f); out-of-[0,32) -> 255 (zero bases).
__global__ __launch_bounds__(256) void leafk_t(
    const float* __restrict__ x, const float* __restrict__ xminF,
    const float* __restrict__ rdenF, unsigned char* __restrict__ lt) {
    __shared__ unsigned char lsh[256 * 68];    // [i][r], stride 68 (odd dword) -> no 32-way conflicts
    const int t = threadIdx.x;
    const int b0 = blockIdx.x * 64;
    const float xmn = xminF[t], rdn = rdenF[t];
    for (int r = 0; r < 64; ++r) {
        float v = x[(size_t)(b0 + r) * IN_F + t];
        float xn = (v - xmn) * rdn;
        int l = (int)(xn * 32.0f);
        lsh[t * 68 + r] = (l >= 0 && l < 32) ? (unsigned char)l : (unsigned char)255;
    }
    __syncthreads();
    const int lane = t & 63, w = t >> 6;
    const unsigned* lshU = (const unsigned*)lsh;   // row i = lshU[i*17 .. i*17+15]
#pragma unroll
    for (int ib = 0; ib < 16; ++ib) {
        int i = ib * 16 + w * 4 + (lane >> 4);
        unsigned val = lshU[i * 17 + (lane & 15)];
        *(unsigned*)(lt + (size_t)i * BATCH + b0 + (lane & 15) * 4) = val;
    }
}

// ---------------- kernel 4: one-hot GEMM, register-synthesized A fragments ----
// A-fragment identity: lane (rr,kq), ks needs A[m][32ks+8kq+e] which for the one-hot
// matrix is 1.0 iff leaf(m, 2kb+ks)>>3==kq and (leaf&7)==e  (leaf>=32 is 255, never
// matches kq<=3). So A never touches LDS: no Ash, no A-phase, ONE barrier per kb.
// LDS = 16KB (B dbuf only). K-split z=2 (kb [0,66)/[66,132)) + atomicAdd epilogue
// -> 2048 blocks, 8 blocks/CU, 16 waves/CU = 4 waves/SIMD (was 2).
__global__ __launch_bounds__(128, 4) void gemm_kan(
    const float* __restrict__ x,
    const unsigned short* __restrict__ Wb,
    const unsigned char* __restrict__ lt,
    float* __restrict__ out)
{
    __shared__ unsigned short Bsh[2 * 64 * 64];    // 16KB double buffer

    const int t     = threadIdx.x;     // 0..127
    const int lane  = t & 63;
    const int wv    = t >> 6;          // 0,1
    const int mtile = blockIdx.x;
    const int ntile = blockIdx.y;
    const int kbeg  = blockIdx.z * 66;
    const int kend  = kbeg + 66;

    // B glds source base (pre-swizzled by n&7 == lane>>3); wave wv stages rows 32wv..+31
    const unsigned char* bbase = (const unsigned char*)(Wb
        + (size_t)(ntile * 64 + wv * 32 + (lane >> 3)) * KTOT
        + (((lane & 7) ^ (lane >> 3)) << 3));

    const int rr = lane & 15, kq = lane >> 4;
    const size_t lrow0 = (size_t)mtile * 64 + wv * 32 + rr;   // per-lane A-row base

    // B LDS read byte offsets (constant across kb; buffer toggle adds 8192)
    int boff[2][4];
#pragma unroll
    for (int ks = 0; ks < 2; ++ks)
#pragma unroll
        for (int nt = 0; nt < 4; ++nt) {
            int n = nt * 16 + rr, c = ks * 4 + kq;
            boff[ks][nt] = (n << 7) + ((c ^ (n & 7)) << 4);
        }

    // prologue: stage B(kbeg) into buf[kbeg&1], fetch first leaf bytes
    {
        unsigned short* dst = Bsh + (kbeg & 1) * 4096 + wv * 2048;
        const unsigned char* src = bbase + (size_t)kbeg * 128;
#pragma unroll
        for (int q = 0; q < 4; ++q)
            __builtin_amdgcn_global_load_lds(
                (as1cvp)(src + (size_t)q * 8 * KTOT * 2),
                (as3vp)(uint32_t)(uintptr_t)(dst + q * 512), 16, 0, 0);
    }
    int lf[2][2];   // [ks][mt] leaf bytes for current kb
#pragma unroll
    for (int ks = 0; ks < 2; ++ks)
#pragma unroll
        for (int mt = 0; mt < 2; ++mt)
            lf[ks][mt] = lt[(size_t)(kbeg * 2 + ks) * BATCH + lrow0 + mt * 16];
    __syncthreads();

    f32x4 acc[2][4] = {};

    for (int kb = kbeg; kb < kend; ++kb) {
        const int cur = kb & 1;

        // issue B(kb+1) into alt buffer first (max overlap under MFMA below)
        if (kb + 1 < kend) {
            const unsigned char* src = bbase + (size_t)(kb + 1) * 128;
            unsigned short* dst = Bsh + (1 - cur) * 4096 + wv * 2048;
#pragma unroll
            for (int q = 0; q < 4; ++q)
                __builtin_amdgcn_global_load_lds(
                    (as1cvp)(src + (size_t)q * 8 * KTOT * 2),
                    (as3vp)(uint32_t)(uintptr_t)(dst + q * 512), 16, 0, 0);
        }

        // synthesize A fragments in registers
        s16x8 af[2][2];   // [ks][mt]
        if (kb < 128) {
#pragma unroll
            for (int ks = 0; ks < 2; ++ks)
#pragma unroll
                for (int mt = 0; mt < 2; ++mt) {
                    int L = lf[ks][mt];
                    unsigned hot = ((L >> 3) == kq) ? (0x3F80u << ((L & 1) << 4)) : 0u;
                    int slot = (L >> 1) & 3;
                    union { s16x8 v; unsigned u[4]; } a;
                    a.u[0] = (slot == 0) ? hot : 0u;
                    a.u[1] = (slot == 1) ? hot : 0u;
                    a.u[2] = (slot == 2) ? hot : 0u;
                    a.u[3] = (slot == 3) ? hot : 0u;
                    af[ks][mt] = a.v;
                }
        } else {
            // dense relu(x) tail: lane loads its own 8 floats per fragment
#pragma unroll
            for (int ks = 0; ks < 2; ++ks)
#pragma unroll
                for (int mt = 0; mt < 2; ++mt) {
                    const float* xr = x + (lrow0 + mt * 16) * IN_F
                                        + (kb - 128) * 64 + ks * 32 + kq * 8;
                    union { s16x8 v; unsigned short s[8]; } a;
#pragma unroll
                    for (int e = 0; e < 8; ++e) a.s[e] = f2bf(fmaxf(xr[e], 0.0f));
                    af[ks][mt] = a.v;
                }
        }

        // prefetch leaf bytes for kb+1 (land under MFMA)
        if (kb + 1 < kend && kb + 1 < 128) {
#pragma unroll
            for (int ks = 0; ks < 2; ++ks)
#pragma unroll
                for (int mt = 0; mt < 2; ++mt)
                    lf[ks][mt] = lt[(size_t)((kb + 1) * 2 + ks) * BATCH + lrow0 + mt * 16];
        }

        // MFMA on buf[cur]
        const char* bb = (const char*)Bsh + cur * 8192;
#pragma unroll
        for (int ks = 0; ks < 2; ++ks) {
            s16x8 bfr[4];
#pragma unroll
            for (int nt = 0; nt < 4; ++nt)
                bfr[nt] = *(const s16x8*)(bb + boff[ks][nt]);
#pragma unroll
            for (int mt = 0; mt < 2; ++mt)
#pragma unroll
                for (int nt = 0; nt < 4; ++nt)
                    acc[mt][nt] = __builtin_amdgcn_mfma_f32_16x16x32_bf16(
                        af[ks][mt], bfr[nt], acc[mt][nt], 0, 0, 0);
        }
        __syncthreads();   // B(kb+1) glds drained (landed under MFMA); buf swap safe
    }

    // epilogue: C/D layout col=lane&15, row=(lane>>4)*4+reg; K-split -> atomicAdd
    const int rq = lane >> 4;
#pragma unroll
    for (int mt = 0; mt < 2; ++mt)
#pragma unroll
        for (int nt = 0; nt < 4; ++nt)
#pragma unroll
            for (int v = 0; v < 4; ++v) {
                int row = mtile * 64 + wv * 32 + mt * 16 + rq * 4 + v;
                int col = ntile * 64 + nt * 16 + rr;
                atomicAdd(&out[(size_t)row * OUT_F + col], acc[mt][nt][v]);
            }
}

// ---------------- host ----------------
extern "C" void kernel_launch(void* const* d_in, const int* in_sizes, int n_in,
                              void* d_out, int out_size, void* d_ws, size_t ws_size,
                              hipStream_t stream) {
    (void)in_sizes; (void)n_in; (void)out_size; (void)ws_size;
    const float* x  = (const float*)d_in[0];   // [16384,256]
    const float* bw = (const float*)d_in[1];   // [256,256]
    const float* sw = (const float*)d_in[2];   // [256,256,31]
    const float* sc = (const float*)d_in[3];   // [256,256]
    float* out = (float*)d_out;

    char* ws = (char*)d_ws;
    unsigned short* Wb   = (unsigned short*)ws;                 // 4,325,376 B
    unsigned char*  lt   = (unsigned char*)(ws + 4325376);      // 4,194,304 B
    // minmax partials alias the (not-yet-written) lt region: dead before leafk runs
    float* pmn   = (float*)(ws + 4325376);                      // 524,288 B
    float* pmx   = (float*)(ws + 4325376 + 524288);             // 524,288 B
    float* xminF = (float*)(ws + 8519680);                      // 1,024 B
    float* rdenF = (float*)(ws + 8520704);                      // 1,024 B

    hipMemsetAsync(out, 0, (size_t)BATCH * OUT_F * 4, stream);  // K-split accumulates

    minmax_part<<<512, 256, 0, stream>>>(x, pmn, pmx);
    minmax_reduce<<<256, 64, 0, stream>>>(pmn, pmx, xminF, rdenF);
    build_wb<<<dim3(256, 4), 256, 0, stream>>>(bw, sw, sc, Wb);
    leafk_t<<<256, 256, 0, stream>>>(x, xminF, rdenF, lt);
    gemm_kan<<<dim3(256, 4, 2), 128, 0, stream>>>(x, Wb, lt, out);
}

// Round 3
// 175.568 us; speedup vs baseline: 1.1439x; 1.0164x over previous
//
#include <hip/hip_runtime.h>
#include <stdint.h>

typedef short s16x8 __attribute__((ext_vector_type(8)));
typedef float f32x4 __attribute__((ext_vector_type(4)));
typedef unsigned long long u64;

#define IN_F   256
#define OUT_F  256
#define BATCH  16384
#define NB     31
#define KONE   8192
#define KTOT   8448

typedef const __attribute__((address_space(1))) void* as1cvp;
typedef __attribute__((address_space(3))) void* as3vp;

__device__ __forceinline__ unsigned short f2bf(float f) {
    unsigned u = __float_as_uint(f);
    u += 0x7FFFu + ((u >> 16) & 1u);   // RNE
    return (unsigned short)(u >> 16);
}

// ---------------- kernel 1a: per-block column min/max partials ----------------
__global__ void minmax_part(const float* __restrict__ x,
                            float* __restrict__ pmn, float* __restrict__ pmx) {
    const int t = threadIdx.x;
    const int b0 = blockIdx.x * 32;
    float mn = 3.4e38f, mx = -3.4e38f;
    for (int r = 0; r < 32; ++r) {
        float v = x[(size_t)(b0 + r) * IN_F + t];
        mn = fminf(mn, v);
        mx = fmaxf(mx, v);
    }
    pmn[blockIdx.x * 256 + t] = mn;
    pmx[blockIdx.x * 256 + t] = mx;
}

// ---------------- kernel 1b: reduce partials, emit xmin & rden ----------------
__global__ __launch_bounds__(64) void minmax_reduce(
    const float* __restrict__ pmn, const float* __restrict__ pmx,
    float* __restrict__ xminF, float* __restrict__ rdenF) {
    const int j = blockIdx.x;
    const int lane = threadIdx.x;
    float mn = 3.4e38f, mx = -3.4e38f;
#pragma unroll
    for (int i = 0; i < 8; ++i) {
        int b = lane * 8 + i;
        mn = fminf(mn, pmn[(size_t)b * 256 + j]);
        mx = fmaxf(mx, pmx[(size_t)b * 256 + j]);
    }
#pragma unroll
    for (int off = 32; off; off >>= 1) {
        mn = fminf(mn, __shfl_down(mn, off));
        mx = fmaxf(mx, __shfl_down(mx, off));
    }
    if (lane == 0) {
        xminF[j] = mn;
        rdenF[j] = 1.0f / (mx - mn + 1e-8f);   // verified chain: rcp-mult
    }
}

// ---------------- kernel 2: build W = [Haar-synthesized V | bw], bf16 -------
// One thread per (o,i): loads the 31 spline weights ONCE into registers
// (old version re-read them 5x per j, 32 j's), writes 64B contiguous.
__global__ __launch_bounds__(256) void build_wb(
    const float* __restrict__ bw, const float* __restrict__ sw,
    const float* __restrict__ sc, unsigned short* __restrict__ Wb) {
    const int o = blockIdx.x, i = threadIdx.x;
    const float s = sc[o * IN_F + i];
    const float* swp = sw + (size_t)(o * IN_F + i) * NB;
    float w[NB];
#pragma unroll
    for (int k = 0; k < NB; ++k) w[k] = swp[k];
    unsigned short* dst = Wb + (size_t)o * KTOT + i * 32;
#pragma unroll
    for (int q = 0; q < 4; ++q) {
        union { s16x8 v; unsigned short s8[8]; } pk;
#pragma unroll
        for (int e = 0; e < 8; ++e) {
            int j = q * 8 + e;
            float acc = 0.f;
#pragma unroll
            for (int l = 0; l < 5; ++l) {
                int kk = (1 << l) - 1 + (j >> (5 - l));
                acc += (((j >> (4 - l)) & 1) ? -w[kk] : w[kk]);
            }
            pk.s8[e] = f2bf(acc * s);
        }
        *(s16x8*)(dst + q * 8) = pk.v;
    }
    Wb[(size_t)o * KTOT + KONE + i] = f2bf(bw[o * IN_F + i]);
}

// ---------------- kernel 3: leaf indices, NATURAL layout lt[b][i] -----------
// xn = (x - xmin) * rden, leaf = (int)(xn*32.0f); out-of-[0,32) -> 255.
// No LDS, no transpose: float4 in -> packed dword out, fully coalesced.
__global__ __launch_bounds__(256) void leafk(
    const float* __restrict__ x, const float* __restrict__ xminF,
    const float* __restrict__ rdenF, unsigned char* __restrict__ lt) {
    const int lane = threadIdx.x & 63, w = threadIdx.x >> 6;
    const int b0 = blockIdx.x * 64;
    const float4 mn = *(const float4*)(xminF + lane * 4);
    const float4 rd = *(const float4*)(rdenF + lane * 4);
#pragma unroll 4
    for (int r = 0; r < 16; ++r) {
        int row = b0 + w * 16 + r;
        float4 v = *(const float4*)(x + (size_t)row * IN_F + lane * 4);
        unsigned b[4];
        float xs[4] = {v.x, v.y, v.z, v.w};
        float ms[4] = {mn.x, mn.y, mn.z, mn.w};
        float rs[4] = {rd.x, rd.y, rd.z, rd.w};
#pragma unroll
        for (int e = 0; e < 4; ++e) {
            float xn = (xs[e] - ms[e]) * rs[e];
            int l = (int)(xn * 32.0f);
            b[e] = (l >= 0 && l < 32) ? (unsigned)l : 255u;
        }
        unsigned pk = b[0] | (b[1] << 8) | (b[2] << 16) | (b[3] << 24);
        *(unsigned*)(lt + (size_t)row * IN_F + lane * 4) = pk;
    }
}

// ---------------- kernel 4: one-hot GEMM, reg-synth A, 128x64 tile, 4 waves --
// Block = 4 waves, M128xN64 tile, wave wv owns rows 32wv..+31 (mt=2 frags).
// Waves of a block land on DIFFERENT SIMDs -> each SIMD hosts 4 waves from 4
// INDEPENDENT blocks (4 blocks/CU): barrier skew in one block is hidden by the
// other three. Leaf bytes: one u64 per 4 kb per M-frag (lt is [b][i], features
// contiguous) extracted with compile-time shifts -- replaces R2's 16 redundant
// byte-loads/kb that doubled VALUBusy. K z-split 68/64 (4-aligned; dense tail
// kb 128..131 lands whole in z=1) + atomicAdd epilogue on zeroed out.
__global__ __launch_bounds__(256, 4) void gemm_kan(
    const float* __restrict__ x,
    const unsigned short* __restrict__ Wb,
    const unsigned char* __restrict__ lt,
    float* __restrict__ out)
{
    __shared__ unsigned short Bsh[2 * 64 * 64];    // 16KB double buffer

    const int t    = threadIdx.x;      // 0..255
    const int lane = t & 63;
    const int wv   = t >> 6;           // 0..3

    // XCD-bijective swizzle (1024 blocks, 8 XCDs): XCD k gets one (ntile,z)
    // slice over all mtiles -> 540KB B panel resident per XCD L2.
    const int bid   = blockIdx.x;
    const int sid   = (bid & 7) * 128 + (bid >> 3);
    const int mtile = sid & 127;
    const int ntile = (sid >> 7) & 3;
    const int zz    = sid >> 9;
    const int kbeg  = zz ? 68 : 0;
    const int kend  = zz ? 132 : 68;

    // B glds source base: wave wv stages N-rows 16wv..16wv+15 (chunks 2wv,2wv+1)
    const unsigned char* bbase = (const unsigned char*)(Wb
        + (size_t)(ntile * 64 + wv * 16 + (lane >> 3)) * KTOT
        + (((lane & 7) ^ (lane >> 3)) << 3));

    const int rr = lane & 15, kq = lane >> 4;
    const int r0 = mtile * 128 + wv * 32 + rr;       // M rows r0, r0+16
    const unsigned char* lp0 = lt + (size_t)r0 * IN_F;
    const unsigned char* lp1 = lt + (size_t)(r0 + 16) * IN_F;

    // B LDS read byte offsets (constant; buffer toggle adds 8192B)
    int boff[2][4];
#pragma unroll
    for (int ks = 0; ks < 2; ++ks)
#pragma unroll
        for (int nt = 0; nt < 4; ++nt) {
            int n = nt * 16 + rr, c = ks * 4 + kq;
            boff[ks][nt] = (n << 7) + ((c ^ (n & 7)) << 4);
        }

    // prologue: stage B(kbeg), load first leaf group
    {
        const unsigned char* src = bbase + (size_t)kbeg * 128;
        unsigned short* dst = Bsh + (kbeg & 1) * 4096 + wv * 1024;
#pragma unroll
        for (int qq = 0; qq < 2; ++qq)
            __builtin_amdgcn_global_load_lds(
                (as1cvp)(src + (size_t)qq * 8 * KTOT * 2),
                (as3vp)(uint32_t)(uintptr_t)(dst + qq * 512), 16, 0, 0);
    }
    u64 L0 = *(const u64*)(lp0 + 2 * kbeg);
    u64 L1 = *(const u64*)(lp1 + 2 * kbeg);
    __syncthreads();

    f32x4 acc[2][4] = {};

    for (int kb0 = kbeg; kb0 < kend; kb0 += 4) {
        // prefetch next leaf group (lands under MFMA; drained by next barrier)
        u64 nL0 = L0, nL1 = L1;
        if (kb0 + 4 < kend && kb0 + 4 < 128) {
            nL0 = *(const u64*)(lp0 + 2 * (kb0 + 4));
            nL1 = *(const u64*)(lp1 + 2 * (kb0 + 4));
        }
        const bool denseg = (kb0 >= 128);   // group-aligned: all-leaf or all-dense
#pragma unroll
        for (int j = 0; j < 4; ++j) {
            const int kb = kb0 + j;
            const int cur = kb & 1;

            // issue B(kb+1) into alt buffer (lands under MFMA below)
            if (kb + 1 < kend) {
                const unsigned char* src = bbase + (size_t)(kb + 1) * 128;
                unsigned short* dst = Bsh + (1 - cur) * 4096 + wv * 1024;
#pragma unroll
                for (int qq = 0; qq < 2; ++qq)
                    __builtin_amdgcn_global_load_lds(
                        (as1cvp)(src + (size_t)qq * 8 * KTOT * 2),
                        (as3vp)(uint32_t)(uintptr_t)(dst + qq * 512), 16, 0, 0);
            }

            // synthesize A fragments in registers
            s16x8 af[2][2];   // [ks][mt]
            if (!denseg) {
#pragma unroll
                for (int ks = 0; ks < 2; ++ks)
#pragma unroll
                    for (int mt = 0; mt < 2; ++mt) {
                        const u64 Lw = mt ? L1 : L0;
                        const int L = (int)((Lw >> (((j << 1) | ks) << 3)) & 255u);
                        unsigned hot = ((L >> 3) == kq) ? (0x3F80u << ((L & 1) << 4)) : 0u;
                        int slot = (L >> 1) & 3;
                        union { s16x8 v; unsigned u[4]; } a;
                        a.u[0] = (slot == 0) ? hot : 0u;
                        a.u[1] = (slot == 1) ? hot : 0u;
                        a.u[2] = (slot == 2) ? hot : 0u;
                        a.u[3] = (slot == 3) ? hot : 0u;
                        af[ks][mt] = a.v;
                    }
            } else {
                // dense relu(x) tail (kb 128..131)
#pragma unroll
                for (int ks = 0; ks < 2; ++ks)
#pragma unroll
                    for (int mt = 0; mt < 2; ++mt) {
                        const float* xr = x + (size_t)(r0 + mt * 16) * IN_F
                                            + (kb - 128) * 64 + ks * 32 + kq * 8;
                        union { s16x8 v; unsigned short s8[8]; } a;
#pragma unroll
                        for (int e = 0; e < 8; ++e) a.s8[e] = f2bf(fmaxf(xr[e], 0.0f));
                        af[ks][mt] = a.v;
                    }
            }

            // MFMA on buf[cur]
            const char* bb = (const char*)Bsh + cur * 8192;
#pragma unroll
            for (int ks = 0; ks < 2; ++ks) {
                s16x8 bfr[4];
#pragma unroll
                for (int nt = 0; nt < 4; ++nt)
                    bfr[nt] = *(const s16x8*)(bb + boff[ks][nt]);
#pragma unroll
                for (int mt = 0; mt < 2; ++mt)
#pragma unroll
                    for (int nt = 0; nt < 4; ++nt)
                        acc[mt][nt] = __builtin_amdgcn_mfma_f32_16x16x32_bf16(
                            af[ks][mt], bfr[nt], acc[mt][nt], 0, 0, 0);
            }
            __syncthreads();   // B(kb+1) glds drained (landed under MFMA)
        }
        L0 = nL0; L1 = nL1;
    }

    // epilogue: C/D layout col=lane&15, row=(lane>>4)*4+reg; K-split -> atomicAdd
    const int rq = lane >> 4;
#pragma unroll
    for (int mt = 0; mt < 2; ++mt)
#pragma unroll
        for (int nt = 0; nt < 4; ++nt)
#pragma unroll
            for (int v = 0; v < 4; ++v) {
                int row = mtile * 128 + wv * 32 + mt * 16 + rq * 4 + v;
                int col = ntile * 64 + nt * 16 + rr;
                atomicAdd(&out[(size_t)row * OUT_F + col], acc[mt][nt][v]);
            }
}

// ---------------- host ----------------
extern "C" void kernel_launch(void* const* d_in, const int* in_sizes, int n_in,
                              void* d_out, int out_size, void* d_ws, size_t ws_size,
                              hipStream_t stream) {
    (void)in_sizes; (void)n_in; (void)out_size; (void)ws_size;
    const float* x  = (const float*)d_in[0];   // [16384,256]
    const float* bw = (const float*)d_in[1];   // [256,256]
    const float* sw = (const float*)d_in[2];   // [256,256,31]
    const float* sc = (const float*)d_in[3];   // [256,256]
    float* out = (float*)d_out;

    char* ws = (char*)d_ws;
    unsigned short* Wb   = (unsigned short*)ws;                 // 4,325,376 B
    unsigned char*  lt   = (unsigned char*)(ws + 4325376);      // 4,194,304 B  [b][i]
    // minmax partials alias the (not-yet-written) lt region
    float* pmn   = (float*)(ws + 4325376);                      // 524,288 B
    float* pmx   = (float*)(ws + 4325376 + 524288);             // 524,288 B
    float* xminF = (float*)(ws + 8519680);                      // 1,024 B
    float* rdenF = (float*)(ws + 8520704);                      // 1,024 B

    hipMemsetAsync(out, 0, (size_t)BATCH * OUT_F * 4, stream);  // K-split accumulates

    minmax_part<<<512, 256, 0, stream>>>(x, pmn, pmx);
    minmax_reduce<<<256, 64, 0, stream>>>(pmn, pmx, xminF, rdenF);
    build_wb<<<256, 256, 0, stream>>>(bw, sw, sc, Wb);
    leafk<<<256, 256, 0, stream>>>(x, xminF, rdenF, lt);
    gemm_kan<<<1024, 256, 0, stream>>>(x, Wb, lt, out);
}